// Round 1
// baseline (1066.189 us; speedup 1.0000x reference)
//
#include <hip/hip_runtime.h>
#include <math.h>

#define N_TOK 32768
#define DIM   256
#define KCODE 4096

// ---- workspace layout (float offsets) ----
#define WS_E2      0                      // [4096]
#define WS_COUNTS  4096                   // [4096]
#define WS_LOSSP   8192                   // [256]
#define WS_SCAL    8448                   // [64]  scal[0]=bias
#define WS_CNORM   8512                   // [4096]
#define WS_IDX     12608                  // int [32768]
#define WS_PVAL    45376                  // [32768*4]
#define WS_PIDX    176448                 // int [32768*4]
#define WS_ET      307520                 // eT [4096*256]
#define WS_DWT     1356096                // dwT [4096*256]
// total = 2404672 floats = ~9.2 MB

// ---- output layout (float offsets) ----
#define OUT_Q      0
#define OUT_LOSS   8388608
#define OUT_PERP   8388609
#define OUT_IDX    8388610
#define OUT_EMB    8421378

typedef float v2f __attribute__((ext_vector_type(2)));

// ||e_k||^2, partials over d with atomics (e2 pre-zeroed)
__global__ void k_e2(const float* __restrict__ emb, float* __restrict__ e2)
{
    int k  = blockIdx.x * 256 + threadIdx.x;
    int d0 = blockIdx.y * 32;
    float s = 0.0f;
#pragma unroll 8
    for (int d = 0; d < 32; ++d) {
        float v = emb[(size_t)(d0 + d) * KCODE + k];
        s += v * v;
    }
    atomicAdd(&e2[k], s);
}

// embeddings [D][K] -> eT [K][D]
__global__ void k_transpose(const float* __restrict__ emb, float* __restrict__ eT)
{
    __shared__ float tile[32][33];
    int t  = threadIdx.x;
    int tx = t & 31, iy = t >> 5;
    int k0 = blockIdx.x * 32, d0 = blockIdx.y * 32;
#pragma unroll
    for (int j = 0; j < 4; ++j)
        tile[iy + 8 * j][tx] = emb[(size_t)(d0 + iy + 8 * j) * KCODE + k0 + tx];
    __syncthreads();
#pragma unroll
    for (int j = 0; j < 4; ++j)
        eT[(size_t)(k0 + iy + 8 * j) * DIM + d0 + tx] = tile[tx][iy + 8 * j];
}

// Distance argmin, split-K. Block: 128 rows x 1024-code slice.
// 256 threads as 16x16, 8x8 micro-tile, packed float2 accumulators.
__global__ __launch_bounds__(256, 3)
void k_argmin(const float* __restrict__ x, const float* __restrict__ emb,
              const float* __restrict__ e2, float* __restrict__ pval,
              int* __restrict__ pidx)
{
    __shared__ __align__(16) float As[32][128];   // A^T: [d][row]
    __shared__ __align__(16) float Bs[32][140];   // [d][code], swizzled +4 per 32
    __shared__ __align__(16) float e2s[128];

    const int t  = threadIdx.x;
    const int tx = t & 15, ty = t >> 4;
    const int row0  = blockIdx.x * 128;
    const int kbase = blockIdx.y * 1024;

    float best[8];
    int   bidx[8];
#pragma unroll
    for (int i = 0; i < 8; ++i) { best[i] = 3.4e38f; bidx[i] = 0; }

    const int la_d4 = t & 7;   // A stage: float4 index along d
    const int la_r  = t >> 3;  // A stage: row 0..31 (+32j)
    const int lb_d  = t >> 3;  // B stage: d row 0..31
    const int lb_c8 = t & 7;   // B stage: float4 col group

    for (int kc = 0; kc < 1024; kc += 128) {
        const int k0 = kbase + kc;
        v2f acc[8][4];
#pragma unroll
        for (int i = 0; i < 8; ++i)
#pragma unroll
            for (int c = 0; c < 4; ++c) { acc[i][c].x = 0.0f; acc[i][c].y = 0.0f; }

        for (int dc = 0; dc < 256; dc += 32) {
            __syncthreads();
            // stage A: x[row0..row0+127][dc..dc+31] -> As[d][r]
#pragma unroll
            for (int j = 0; j < 4; ++j) {
                int rr = la_r + 32 * j;
                float4 v = *(const float4*)&x[(size_t)(row0 + rr) * DIM + dc + la_d4 * 4];
                As[la_d4 * 4 + 0][rr] = v.x;
                As[la_d4 * 4 + 1][rr] = v.y;
                As[la_d4 * 4 + 2][rr] = v.z;
                As[la_d4 * 4 + 3][rr] = v.w;
            }
            // stage B: emb[dc..dc+31][k0..k0+127] -> Bs[d][cmap(c)]
#pragma unroll
            for (int j = 0; j < 4; ++j) {
                int c = lb_c8 * 4 + 32 * j;
                float4 v = *(const float4*)&emb[(size_t)(dc + lb_d) * KCODE + k0 + c];
                *(float4*)&Bs[lb_d][c + 4 * (c >> 5)] = v;
            }
            if (dc == 0 && t < 32)
                *(float4*)&e2s[t * 4] = *(const float4*)&e2[k0 + t * 4];
            __syncthreads();

#pragma unroll 8
            for (int d = 0; d < 32; ++d) {
                float a[8];
                *(float4*)&a[0] = *(const float4*)&As[d][ty * 8];
                *(float4*)&a[4] = *(const float4*)&As[d][ty * 8 + 4];
                const float* bp = &Bs[d][tx * 8 + ((tx >> 2) << 2)];
                float4 b0 = *(const float4*)bp;
                float4 b1 = *(const float4*)(bp + 4);
                v2f b[4];
                b[0].x = b0.x; b[0].y = b0.y;
                b[1].x = b0.z; b[1].y = b0.w;
                b[2].x = b1.x; b[2].y = b1.y;
                b[3].x = b1.z; b[3].y = b1.w;
#pragma unroll
                for (int i = 0; i < 8; ++i)
#pragma unroll
                    for (int c = 0; c < 4; ++c)
                        acc[i][c] += a[i] * b[c];   // hope: v_pk_fma_f32
            }
        }
        // fold into running argmin (codes ascending => strict < keeps lowest idx)
#pragma unroll
        for (int i = 0; i < 8; ++i) {
#pragma unroll
            for (int c = 0; c < 4; ++c) {
                int kk = k0 + tx * 8 + c * 2;
                float v0 = e2s[tx * 8 + c * 2]     - 2.0f * acc[i][c].x;
                float v1 = e2s[tx * 8 + c * 2 + 1] - 2.0f * acc[i][c].y;
                if (v0 < best[i]) { best[i] = v0; bidx[i] = kk; }
                if (v1 < best[i]) { best[i] = v1; bidx[i] = kk + 1; }
            }
        }
    }

    // block reduction across the 16 tx threads per row
    __syncthreads();
    float* vals = &As[0][0];          // 128*16 floats
    int*   idxs = (int*)&Bs[0][0];    // 128*16 ints
#pragma unroll
    for (int i = 0; i < 8; ++i) {
        int r = ty * 8 + i;
        vals[r * 16 + tx] = best[i];
        idxs[r * 16 + tx] = bidx[i];
    }
    __syncthreads();
    if (t < 128) {
        float bv = vals[t * 16];
        int   bi = idxs[t * 16];
#pragma unroll
        for (int j = 1; j < 16; ++j) {
            float v = vals[t * 16 + j];
            int  ii = idxs[t * 16 + j];
            if (v < bv || (v == bv && ii < bi)) { bv = v; bi = ii; }
        }
        pval[(size_t)(row0 + t) * 4 + blockIdx.y] = bv;
        pidx[(size_t)(row0 + t) * 4 + blockIdx.y] = bi;
    }
}

__global__ void k_merge(const float* __restrict__ pval, const int* __restrict__ pidx,
                        int* __restrict__ idx_out)
{
    int n = blockIdx.x * 256 + threadIdx.x;
    float bv = pval[(size_t)n * 4];
    int   bi = pidx[(size_t)n * 4];
#pragma unroll
    for (int s = 1; s < 4; ++s) {
        float v = pval[(size_t)n * 4 + s];
        int  ii = pidx[(size_t)n * 4 + s];
        if (v < bv || (v == bv && ii < bi)) { bv = v; bi = ii; }
    }
    idx_out[n] = bi;
}

// one wave per row: quantized copy, (q-x)^2 loss, counts, dwT scatter, idx float
__global__ void k_gather(const float* __restrict__ x, const float* __restrict__ eT,
                         const int* __restrict__ idx, float* __restrict__ out_q,
                         float* __restrict__ out_idxf, float* __restrict__ counts,
                         float* __restrict__ dwT, float* __restrict__ lossp)
{
    int t = threadIdx.x;
    int lane = t & 63, w = t >> 6;
    int n = blockIdx.x * 4 + w;
    int k = idx[n];
    float4 xv = *(const float4*)&x[(size_t)n * DIM + lane * 4];
    float4 ev = *(const float4*)&eT[(size_t)k * DIM + lane * 4];
    *(float4*)&out_q[(size_t)n * DIM + lane * 4] = ev;
    float dx = ev.x - xv.x, dy = ev.y - xv.y, dz = ev.z - xv.z, dw = ev.w - xv.w;
    float s = dx * dx + dy * dy + dz * dz + dw * dw;
#pragma unroll
    for (int off = 32; off > 0; off >>= 1) s += __shfl_down(s, off, 64);
    float* dp = &dwT[(size_t)k * DIM + lane * 4];
    atomicAdd(dp + 0, xv.x);
    atomicAdd(dp + 1, xv.y);
    atomicAdd(dp + 2, xv.z);
    atomicAdd(dp + 3, xv.w);
    if (lane == 0) {
        atomicAdd(&counts[k], 1.0f);
        atomicAdd(&lossp[blockIdx.x & 255], s);
        out_idxf[n] = (float)k;
    }
}

__global__ void k_finalize(const float* __restrict__ counts, const float* __restrict__ lossp,
                           const float* __restrict__ ema_counter,
                           const float* __restrict__ ema_cluster,
                           float* __restrict__ cnorm, float* __restrict__ scal,
                           float* __restrict__ out)
{
    __shared__ float red[256];
    int t = threadIdx.x;
    float ls = lossp[t];
    float ent = 0.0f, casum = 0.0f;
    float ca[16];
#pragma unroll
    for (int j = 0; j < 16; ++j) {
        int k = j * 256 + t;
        float c = counts[k];
        float p = c * (1.0f / 32768.0f);
        ent += p * logf(p + 1e-10f);
        ca[j] = ema_cluster[k] * 0.99f + c * 0.01f;   // cluster_hidden
        casum += ca[j];
    }
    red[t] = ls; __syncthreads();
    for (int o = 128; o > 0; o >>= 1) { if (t < o) red[t] += red[t + o]; __syncthreads(); }
    float loss_tot = red[0]; __syncthreads();
    red[t] = ent; __syncthreads();
    for (int o = 128; o > 0; o >>= 1) { if (t < o) red[t] += red[t + o]; __syncthreads(); }
    float ent_tot = red[0]; __syncthreads();
    red[t] = casum; __syncthreads();
    for (int o = 128; o > 0; o >>= 1) { if (t < o) red[t] += red[t + o]; __syncthreads(); }
    float casum_tot = red[0]; __syncthreads();

    float bias = 1.0f - powf(0.99f, ema_counter[0] + 1.0f);
    float n = casum_tot / bias;                 // sum(cluster_avg)
    float inv = n / (n + 4096.0f * 1e-5f);
#pragma unroll
    for (int j = 0; j < 16; ++j) {
        int k = j * 256 + t;
        cnorm[k] = (ca[j] / bias + 1e-5f) * inv;
    }
    if (t == 0) {
        out[OUT_LOSS] = 1.25f * loss_tot * (1.0f / (32768.0f * 256.0f));
        out[OUT_PERP] = expf(-ent_tot);
        scal[0] = bias;
    }
}

// new_embeddings[d][k] = (ema_dw*DECAY + dwT^T*(1-DECAY))/bias / cnorm[k]
__global__ void k_newemb(const float* __restrict__ dwT, const float* __restrict__ ema_dw,
                         const float* __restrict__ cnorm, const float* __restrict__ scal,
                         float* __restrict__ out_emb)
{
    __shared__ float tile[32][33];
    int t = threadIdx.x;
    int tx = t & 31, iy = t >> 5;
    int k0 = blockIdx.x * 32, d0 = blockIdx.y * 32;
#pragma unroll
    for (int j = 0; j < 4; ++j)
        tile[iy + 8 * j][tx] = dwT[(size_t)(k0 + iy + 8 * j) * DIM + d0 + tx];
    __syncthreads();
    float inv_bias = 1.0f / scal[0];
    float cn = cnorm[k0 + tx];
#pragma unroll
    for (int j = 0; j < 4; ++j) {
        int d = d0 + iy + 8 * j;
        float dwv = tile[tx][iy + 8 * j];
        float hid = ema_dw[(size_t)d * KCODE + k0 + tx] * 0.99f + dwv * 0.01f;
        out_emb[(size_t)d * KCODE + k0 + tx] = hid * inv_bias / cn;
    }
}

extern "C" void kernel_launch(void* const* d_in, const int* in_sizes, int n_in,
                              void* d_out, int out_size, void* d_ws, size_t ws_size,
                              hipStream_t stream)
{
    const float* x           = (const float*)d_in[0];
    const float* emb         = (const float*)d_in[1];
    const float* ema_counter = (const float*)d_in[2];
    const float* ema_cluster = (const float*)d_in[3];
    const float* ema_dw      = (const float*)d_in[4];
    float* out = (float*)d_out;
    float* ws  = (float*)d_ws;

    float* e2     = ws + WS_E2;
    float* counts = ws + WS_COUNTS;
    float* lossp  = ws + WS_LOSSP;
    float* scal   = ws + WS_SCAL;
    float* cnorm  = ws + WS_CNORM;
    int*   idxw   = (int*)(ws + WS_IDX);
    float* pval   = ws + WS_PVAL;
    int*   pidx   = (int*)(ws + WS_PIDX);
    float* eT     = ws + WS_ET;
    float* dwT    = ws + WS_DWT;

    // zero: e2 + counts + loss partials + scalars, and dwT accumulator
    hipMemsetAsync(e2, 0, (size_t)WS_CNORM * sizeof(float), stream);
    hipMemsetAsync(dwT, 0, (size_t)KCODE * DIM * sizeof(float), stream);

    k_e2<<<dim3(16, 8), 256, 0, stream>>>(emb, e2);
    k_transpose<<<dim3(128, 8), 256, 0, stream>>>(emb, eT);
    k_argmin<<<dim3(256, 4), 256, 0, stream>>>(x, emb, e2, pval, pidx);
    k_merge<<<128, 256, 0, stream>>>(pval, pidx, idxw);
    k_gather<<<8192, 256, 0, stream>>>(x, eT, idxw, out + OUT_Q, out + OUT_IDX,
                                       counts, dwT, lossp);
    k_finalize<<<1, 256, 0, stream>>>(counts, lossp, ema_counter, ema_cluster,
                                      cnorm, scal, out);
    k_newemb<<<dim3(128, 8), 256, 0, stream>>>(dwT, ema_dw, cnorm, scal, out + OUT_EMB);
}